// Round 14
// baseline (30.870 us; speedup 1.0000x reference)
//
#include <hip/hip_runtime.h>
#include <math.h>

#define NVOX 16384
#define NRAYS 2048
#define CAP 256             // per-ray hit capacity (expected ~15-40 hits)
#define BLK 1024
#define RPB 4               // rays per block; phase 2 uses one wave per ray
#define NIT (NVOX / (BLK * 4))   // 4 voxel-quad iterations per thread
#define STOPT 0.01f
#define FARP 100.0f

// Single-node flat rasterizer (R11 structure + full up-front load prefetch).
// Centered slab test: tc = fma(p,iv,of); tn_ax = fma(-s,ai2,tc); tf_ax = fma(s,ai2,tc)
// with ai2 = 0.5*|iv|.  All 16 float4 loads issued before any compute -> 16
// outstanding dwordx4/thread; compute overlaps the vmcnt drain.
__global__ __launch_bounds__(BLK, 4) void raster_flat_kernel(
    const float* __restrict__ pos,   // (NVOX,3)
    const float* __restrict__ siz,   // (NVOX,)
    const float* __restrict__ den,   // (NVOX,)
    const float* __restrict__ col,   // (NVOX,3)
    const float* __restrict__ rob,   // (NRAYS,3)
    const float* __restrict__ rdb,   // (NRAYS,3)
    float* __restrict__ out)         // rgb[NRAYS*3] | depth[NRAYS] | weights[NRAYS]
{
    __shared__ float s_key[RPB][CAP];
    __shared__ float s_op [RPB][CAP];
    __shared__ int   s_cid[RPB][CAP];
    __shared__ int   s_cnt[RPB];

    const int tid  = threadIdx.x;
    const int ray0 = blockIdx.x * RPB;
    if (tid < RPB) s_cnt[tid] = 0;
    __syncthreads();

    // per-ray constants (block-uniform addresses -> scalar loads)
    float ivx[RPB], ivy[RPB], ivz[RPB];      // 1/d
    float aix[RPB], aiy[RPB], aiz[RPB];      // 0.5*|1/d|
    float ofx[RPB], ofy[RPB], ofz[RPB];      // -o/d
#pragma unroll
    for (int r = 0; r < RPB; ++r) {
        const int ray = ray0 + r;
        const float ox = rob[ray*3], oy = rob[ray*3+1], oz = rob[ray*3+2];
        const float dx = rdb[ray*3], dy = rdb[ray*3+1], dz = rdb[ray*3+2];
        ivx[r] = 1.0f/dx;      ivy[r] = 1.0f/dy;      ivz[r] = 1.0f/dz;
        aix[r] = 0.5f*fabsf(ivx[r]); aiy[r] = 0.5f*fabsf(ivy[r]); aiz[r] = 0.5f*fabsf(ivz[r]);
        ofx[r] = -ox*ivx[r];   ofy[r] = -oy*ivy[r];   ofz[r] = -oz*ivz[r];
    }

    const float4* __restrict__ pos4 = (const float4*)pos;   // 12288 float4s
    const float4* __restrict__ siz4 = (const float4*)siz;   // 4096 float4s

    // ---- Phase 1a: issue ALL loads up front (16 dwordx4 in flight/thread) ----
    float4 P0[NIT], P1[NIT], P2[NIT], S4[NIT];
#pragma unroll
    for (int k = 0; k < NIT; ++k) {
        const int g = tid + k * BLK;
        P0[k] = pos4[3*g + 0];
        P1[k] = pos4[3*g + 1];
        P2[k] = pos4[3*g + 2];
        S4[k] = siz4[g];
    }

    // ---- Phase 1b: slab-test 4 voxels x NIT iterations x RPB rays ----
#pragma unroll
    for (int k = 0; k < NIT; ++k) {
        const int v0 = 4 * (tid + k * BLK);
        float vx[4], vy[4], vz[4], vs[4];
        vx[0] = P0[k].x; vy[0] = P0[k].y; vz[0] = P0[k].z; vs[0] = S4[k].x;
        vx[1] = P0[k].w; vy[1] = P1[k].x; vz[1] = P1[k].y; vs[1] = S4[k].y;
        vx[2] = P1[k].z; vy[2] = P1[k].w; vz[2] = P2[k].x; vs[2] = S4[k].z;
        vx[3] = P2[k].y; vy[3] = P2[k].z; vz[3] = P2[k].w; vs[3] = S4[k].w;

#pragma unroll
        for (int q = 0; q < 4; ++q) {
            const float sz = vs[q];
            const float px = vx[q], py = vy[q], pz = vz[q];
#pragma unroll
            for (int r = 0; r < RPB; ++r) {
                const float tcx = fmaf(px, ivx[r], ofx[r]);
                const float tcy = fmaf(py, ivy[r], ofy[r]);
                const float tcz = fmaf(pz, ivz[r], ofz[r]);
                const float tnx = fmaf(-sz, aix[r], tcx);
                const float tny = fmaf(-sz, aiy[r], tcy);
                const float tnz = fmaf(-sz, aiz[r], tcz);
                const float tfx = fmaf( sz, aix[r], tcx);
                const float tfy = fmaf( sz, aiy[r], tcy);
                const float tfz = fmaf( sz, aiz[r], tcz);
                const float tn = fmaxf(fmaxf(tnx, tny), tnz);   // v_max3
                const float tf = fminf(fminf(tfx, tfy), tfz);   // v_min3
                if (tf > tn && tf > 0.0f) {
                    const int v = v0 + q;
                    const float op = 1.0f - expf(-expf(den[v]) * (tf - tn) * (1.0f/7.0f));
                    const int kk = atomicAdd(&s_cnt[r], 1);
                    if (kk < CAP) { s_key[r][kk] = tn; s_op[r][kk] = op; s_cid[r][kk] = v; }
                }
            }
        }
    }
    __syncthreads();

    // Phase 2: wave wv composites ray ray0+wv via O(n^2) exclusive product
    // (reference semantics: w_i = T_excl_i*op_i if T_excl_i >= STOP_T, order-free)
    const int wv = tid >> 6, lane = tid & 63;
    if (wv < RPB) {
        const int n = min(s_cnt[wv], CAP);
        float ar = 0.f, ag = 0.f, ab = 0.f, ad = 0.f, aw = 0.f;
        for (int i = lane; i < n; i += 64) {
            const float ti = s_key[wv][i], oi = s_op[wv][i];
            float T = 1.0f;
            for (int j = 0; j < n; ++j)
                T *= (s_key[wv][j] < ti) ? (1.0f - s_op[wv][j]) : 1.0f;   // LDS broadcast
            const float w = (T >= STOPT) ? T * oi : 0.0f;
            const int c = s_cid[wv][i];
            ar += w * col[c*3+0];
            ag += w * col[c*3+1];
            ab += w * col[c*3+2];
            ad += w * ti;
            aw += w;
        }
#pragma unroll
        for (int off = 32; off > 0; off >>= 1) {
            ar += __shfl_down(ar, off);
            ag += __shfl_down(ag, off);
            ab += __shfl_down(ab, off);
            ad += __shfl_down(ad, off);
            aw += __shfl_down(aw, off);
        }
        if (lane == 0) {
            const int ray = ray0 + wv;
            out[ray*3+0] = ar;
            out[ray*3+1] = ag;
            out[ray*3+2] = ab;
            out[NRAYS*3 + ray] = (n > 0) ? ad : FARP;
            out[NRAYS*4 + ray] = aw;
        }
    }
}

extern "C" void kernel_launch(void* const* d_in, const int* in_sizes, int n_in,
                              void* d_out, int out_size, void* d_ws, size_t ws_size,
                              hipStream_t stream) {
    const float* pos = (const float*)d_in[0];
    const float* siz = (const float*)d_in[1];
    const float* den = (const float*)d_in[2];
    const float* col = (const float*)d_in[3];
    const float* rob = (const float*)d_in[4];
    const float* rdb = (const float*)d_in[5];
    float* out = (float*)d_out;

    raster_flat_kernel<<<NRAYS / RPB, BLK, 0, stream>>>(pos, siz, den, col, rob, rdb, out);
}

// Round 15
// 30.413 us; speedup vs baseline: 1.0150x; 1.0150x over previous
//
#include <hip/hip_runtime.h>
#include <math.h>

#define NVOX 16384
#define NRAYS 2048
#define CAP 256             // per-ray hit capacity (expected ~15-40 hits)
#define BLK 1024
#define RPB 4               // rays per block; phase 2 uses one wave per ray
#define STOPT 0.01f
#define FARP 100.0f

typedef float f2 __attribute__((ext_vector_type(2)));

// Single-node flat rasterizer (R11 structure), slab math packed 2 voxels/inst
// via v_pk_fma_f32: tc = pk_fma(p2, iv, of); tn = pk_fma(-s2, ai, tc);
// tf = pk_fma(s2, ai, tc). max3/min3/cmp scalar on the pair halves.
__global__ __launch_bounds__(BLK, 4) void raster_flat_kernel(
    const float* __restrict__ pos,   // (NVOX,3)
    const float* __restrict__ siz,   // (NVOX,)
    const float* __restrict__ den,   // (NVOX,)
    const float* __restrict__ col,   // (NVOX,3)
    const float* __restrict__ rob,   // (NRAYS,3)
    const float* __restrict__ rdb,   // (NRAYS,3)
    float* __restrict__ out)         // rgb[NRAYS*3] | depth[NRAYS] | weights[NRAYS]
{
    __shared__ float s_key[RPB][CAP];
    __shared__ float s_op [RPB][CAP];
    __shared__ int   s_cid[RPB][CAP];
    __shared__ int   s_cnt[RPB];

    const int tid  = threadIdx.x;
    const int ray0 = blockIdx.x * RPB;
    if (tid < RPB) s_cnt[tid] = 0;
    __syncthreads();

    // per-ray constants (block-uniform addresses -> scalar loads)
    float ivx[RPB], ivy[RPB], ivz[RPB];      // 1/d
    float aix[RPB], aiy[RPB], aiz[RPB];      // 0.5*|1/d|
    float ofx[RPB], ofy[RPB], ofz[RPB];      // -o/d
#pragma unroll
    for (int r = 0; r < RPB; ++r) {
        const int ray = ray0 + r;
        const float ox = rob[ray*3], oy = rob[ray*3+1], oz = rob[ray*3+2];
        const float dx = rdb[ray*3], dy = rdb[ray*3+1], dz = rdb[ray*3+2];
        ivx[r] = 1.0f/dx;      ivy[r] = 1.0f/dy;      ivz[r] = 1.0f/dz;
        aix[r] = 0.5f*fabsf(ivx[r]); aiy[r] = 0.5f*fabsf(ivy[r]); aiz[r] = 0.5f*fabsf(ivz[r]);
        ofx[r] = -ox*ivx[r];   ofy[r] = -oy*ivy[r];   ofz[r] = -oz*ivz[r];
    }

    const float4* __restrict__ pos4 = (const float4*)pos;   // 12288 float4s
    const float4* __restrict__ siz4 = (const float4*)siz;   // 4096 float4s

    // Phase 1: slab-test every voxel against RPB rays; push hits to LDS.
#pragma unroll
    for (int k = 0; k < NVOX / (BLK * 4); ++k) {
        const int g  = tid + k * BLK;        // float4-group index
        const float4 p0 = pos4[3*g + 0];
        const float4 p1 = pos4[3*g + 1];
        const float4 p2 = pos4[3*g + 2];
        const float4 s  = siz4[g];
        const int v0 = 4 * g;

        float vx[4], vy[4], vz[4], vs[4];
        vx[0] = p0.x; vy[0] = p0.y; vz[0] = p0.z; vs[0] = s.x;
        vx[1] = p0.w; vy[1] = p1.x; vz[1] = p1.y; vs[1] = s.y;
        vx[2] = p1.z; vy[2] = p1.w; vz[2] = p2.x; vs[2] = s.z;
        vx[3] = p2.y; vy[3] = p2.z; vz[3] = p2.w; vs[3] = s.w;

#pragma unroll
        for (int qp = 0; qp < 2; ++qp) {     // voxel pair
            const f2 pxp = { vx[2*qp], vx[2*qp+1] };
            const f2 pyp = { vy[2*qp], vy[2*qp+1] };
            const f2 pzp = { vz[2*qp], vz[2*qp+1] };
            const f2 szp = { vs[2*qp], vs[2*qp+1] };
#pragma unroll
            for (int r = 0; r < RPB; ++r) {
                const f2 tcx = __builtin_elementwise_fma(pxp, (f2)ivx[r], (f2)ofx[r]);
                const f2 tcy = __builtin_elementwise_fma(pyp, (f2)ivy[r], (f2)ofy[r]);
                const f2 tcz = __builtin_elementwise_fma(pzp, (f2)ivz[r], (f2)ofz[r]);
                const f2 tnx = __builtin_elementwise_fma(-szp, (f2)aix[r], tcx);
                const f2 tny = __builtin_elementwise_fma(-szp, (f2)aiy[r], tcy);
                const f2 tnz = __builtin_elementwise_fma(-szp, (f2)aiz[r], tcz);
                const f2 tfx = __builtin_elementwise_fma( szp, (f2)aix[r], tcx);
                const f2 tfy = __builtin_elementwise_fma( szp, (f2)aiy[r], tcy);
                const f2 tfz = __builtin_elementwise_fma( szp, (f2)aiz[r], tcz);
#pragma unroll
                for (int h = 0; h < 2; ++h) {
                    const float tn = fmaxf(fmaxf(tnx[h], tny[h]), tnz[h]);   // v_max3
                    const float tf = fminf(fminf(tfx[h], tfy[h]), tfz[h]);   // v_min3
                    if (tf > tn && tf > 0.0f) {
                        const int v = v0 + 2*qp + h;
                        const float op = 1.0f - expf(-expf(den[v]) * (tf - tn) * (1.0f/7.0f));
                        const int kk = atomicAdd(&s_cnt[r], 1);
                        if (kk < CAP) { s_key[r][kk] = tn; s_op[r][kk] = op; s_cid[r][kk] = v; }
                    }
                }
            }
        }
    }
    __syncthreads();

    // Phase 2: wave wv composites ray ray0+wv via O(n^2) exclusive product
    // (reference semantics: w_i = T_excl_i*op_i if T_excl_i >= STOP_T, order-free)
    const int wv = tid >> 6, lane = tid & 63;
    if (wv < RPB) {
        const int n = min(s_cnt[wv], CAP);
        float ar = 0.f, ag = 0.f, ab = 0.f, ad = 0.f, aw = 0.f;
        for (int i = lane; i < n; i += 64) {
            const float ti = s_key[wv][i], oi = s_op[wv][i];
            float T = 1.0f;
            for (int j = 0; j < n; ++j)
                T *= (s_key[wv][j] < ti) ? (1.0f - s_op[wv][j]) : 1.0f;   // LDS broadcast
            const float w = (T >= STOPT) ? T * oi : 0.0f;
            const int c = s_cid[wv][i];
            ar += w * col[c*3+0];
            ag += w * col[c*3+1];
            ab += w * col[c*3+2];
            ad += w * ti;
            aw += w;
        }
#pragma unroll
        for (int off = 32; off > 0; off >>= 1) {
            ar += __shfl_down(ar, off);
            ag += __shfl_down(ag, off);
            ab += __shfl_down(ab, off);
            ad += __shfl_down(ad, off);
            aw += __shfl_down(aw, off);
        }
        if (lane == 0) {
            const int ray = ray0 + wv;
            out[ray*3+0] = ar;
            out[ray*3+1] = ag;
            out[ray*3+2] = ab;
            out[NRAYS*3 + ray] = (n > 0) ? ad : FARP;
            out[NRAYS*4 + ray] = aw;
        }
    }
}

extern "C" void kernel_launch(void* const* d_in, const int* in_sizes, int n_in,
                              void* d_out, int out_size, void* d_ws, size_t ws_size,
                              hipStream_t stream) {
    const float* pos = (const float*)d_in[0];
    const float* siz = (const float*)d_in[1];
    const float* den = (const float*)d_in[2];
    const float* col = (const float*)d_in[3];
    const float* rob = (const float*)d_in[4];
    const float* rdb = (const float*)d_in[5];
    float* out = (float*)d_out;

    raster_flat_kernel<<<NRAYS / RPB, BLK, 0, stream>>>(pos, siz, den, col, rob, rdb, out);
}

// Round 16
// 23.850 us; speedup vs baseline: 1.2943x; 1.2752x over previous
//
#include <hip/hip_runtime.h>
#include <math.h>

#define NVOX 16384
#define NRAYS 2048
#define CAP 256             // per-ray hit capacity (expected ~15-40 hits)
#define BLK 1024
#define RPB 4               // rays per block; phase 2 uses one wave per ray
#define STOPT 0.01f
#define FARP 100.0f

// Single-node flat rasterizer (exact R11 — empirical optimum).
// Centered slab test: tc = fma(p,iv,of); tn_ax = fma(-h,|iv|,tc); tf_ax = fma(h,|iv|,tc)
// => 9 fma + max3 + min3 + 2 cmp per test (no per-axis min/max, no bmin/bmax prep).
__global__ __launch_bounds__(BLK, 4) void raster_flat_kernel(
    const float* __restrict__ pos,   // (NVOX,3)
    const float* __restrict__ siz,   // (NVOX,)
    const float* __restrict__ den,   // (NVOX,)
    const float* __restrict__ col,   // (NVOX,3)
    const float* __restrict__ rob,   // (NRAYS,3)
    const float* __restrict__ rdb,   // (NRAYS,3)
    float* __restrict__ out)         // rgb[NRAYS*3] | depth[NRAYS] | weights[NRAYS]
{
    __shared__ float s_key[RPB][CAP];
    __shared__ float s_op [RPB][CAP];
    __shared__ int   s_cid[RPB][CAP];
    __shared__ int   s_cnt[RPB];

    const int tid  = threadIdx.x;
    const int ray0 = blockIdx.x * RPB;
    if (tid < RPB) s_cnt[tid] = 0;
    __syncthreads();

    // per-ray constants (block-uniform addresses -> scalar loads)
    float ivx[RPB], ivy[RPB], ivz[RPB];      // 1/d
    float aix[RPB], aiy[RPB], aiz[RPB];      // |1/d|
    float ofx[RPB], ofy[RPB], ofz[RPB];      // -o/d
#pragma unroll
    for (int r = 0; r < RPB; ++r) {
        const int ray = ray0 + r;
        const float ox = rob[ray*3], oy = rob[ray*3+1], oz = rob[ray*3+2];
        const float dx = rdb[ray*3], dy = rdb[ray*3+1], dz = rdb[ray*3+2];
        ivx[r] = 1.0f/dx;      ivy[r] = 1.0f/dy;      ivz[r] = 1.0f/dz;
        aix[r] = fabsf(ivx[r]); aiy[r] = fabsf(ivy[r]); aiz[r] = fabsf(ivz[r]);
        ofx[r] = -ox*ivx[r];   ofy[r] = -oy*ivy[r];   ofz[r] = -oz*ivz[r];
    }

    const float4* __restrict__ pos4 = (const float4*)pos;   // 12288 float4s
    const float4* __restrict__ siz4 = (const float4*)siz;   // 4096 float4s

    // Phase 1: slab-test every voxel against RPB rays; push hits to LDS.
    // Each thread handles 4 consecutive voxels per iteration (vectorized loads).
#pragma unroll
    for (int k = 0; k < NVOX / (BLK * 4); ++k) {
        const int g  = tid + k * BLK;        // float4-group index
        const float4 p0 = pos4[3*g + 0];
        const float4 p1 = pos4[3*g + 1];
        const float4 p2 = pos4[3*g + 2];
        const float4 s  = siz4[g];
        const int v0 = 4 * g;

        float vx[4], vy[4], vz[4], vh[4];
        vx[0] = p0.x; vy[0] = p0.y; vz[0] = p0.z; vh[0] = s.x;
        vx[1] = p0.w; vy[1] = p1.x; vz[1] = p1.y; vh[1] = s.y;
        vx[2] = p1.z; vy[2] = p1.w; vz[2] = p2.x; vh[2] = s.z;
        vx[3] = p2.y; vy[3] = p2.z; vz[3] = p2.w; vh[3] = s.w;

#pragma unroll
        for (int q = 0; q < 4; ++q) {
            const float h = vh[q] * 0.5f;
            const float px = vx[q], py = vy[q], pz = vz[q];
#pragma unroll
            for (int r = 0; r < RPB; ++r) {
                const float tcx = fmaf(px, ivx[r], ofx[r]);
                const float tcy = fmaf(py, ivy[r], ofy[r]);
                const float tcz = fmaf(pz, ivz[r], ofz[r]);
                const float tnx = fmaf(-h, aix[r], tcx);
                const float tny = fmaf(-h, aiy[r], tcy);
                const float tnz = fmaf(-h, aiz[r], tcz);
                const float tfx = fmaf( h, aix[r], tcx);
                const float tfy = fmaf( h, aiy[r], tcy);
                const float tfz = fmaf( h, aiz[r], tcz);
                const float tn = fmaxf(fmaxf(tnx, tny), tnz);   // v_max3
                const float tf = fminf(fminf(tfx, tfy), tfz);   // v_min3
                if (tf > tn && tf > 0.0f) {
                    const int v = v0 + q;
                    const float op = 1.0f - expf(-expf(den[v]) * (tf - tn) * (1.0f/7.0f));
                    const int kk = atomicAdd(&s_cnt[r], 1);
                    if (kk < CAP) { s_key[r][kk] = tn; s_op[r][kk] = op; s_cid[r][kk] = v; }
                }
            }
        }
    }
    __syncthreads();

    // Phase 2: wave wv composites ray ray0+wv via O(n^2) exclusive product
    // (reference semantics: w_i = T_excl_i*op_i if T_excl_i >= STOP_T, order-free)
    const int wv = tid >> 6, lane = tid & 63;
    if (wv < RPB) {
        const int n = min(s_cnt[wv], CAP);
        float ar = 0.f, ag = 0.f, ab = 0.f, ad = 0.f, aw = 0.f;
        for (int i = lane; i < n; i += 64) {
            const float ti = s_key[wv][i], oi = s_op[wv][i];
            float T = 1.0f;
            for (int j = 0; j < n; ++j)
                T *= (s_key[wv][j] < ti) ? (1.0f - s_op[wv][j]) : 1.0f;   // LDS broadcast
            const float w = (T >= STOPT) ? T * oi : 0.0f;
            const int c = s_cid[wv][i];
            ar += w * col[c*3+0];
            ag += w * col[c*3+1];
            ab += w * col[c*3+2];
            ad += w * ti;
            aw += w;
        }
#pragma unroll
        for (int off = 32; off > 0; off >>= 1) {
            ar += __shfl_down(ar, off);
            ag += __shfl_down(ag, off);
            ab += __shfl_down(ab, off);
            ad += __shfl_down(ad, off);
            aw += __shfl_down(aw, off);
        }
        if (lane == 0) {
            const int ray = ray0 + wv;
            out[ray*3+0] = ar;
            out[ray*3+1] = ag;
            out[ray*3+2] = ab;
            out[NRAYS*3 + ray] = (n > 0) ? ad : FARP;
            out[NRAYS*4 + ray] = aw;
        }
    }
}

extern "C" void kernel_launch(void* const* d_in, const int* in_sizes, int n_in,
                              void* d_out, int out_size, void* d_ws, size_t ws_size,
                              hipStream_t stream) {
    const float* pos = (const float*)d_in[0];
    const float* siz = (const float*)d_in[1];
    const float* den = (const float*)d_in[2];
    const float* col = (const float*)d_in[3];
    const float* rob = (const float*)d_in[4];
    const float* rdb = (const float*)d_in[5];
    float* out = (float*)d_out;

    raster_flat_kernel<<<NRAYS / RPB, BLK, 0, stream>>>(pos, siz, den, col, rob, rdb, out);
}